// Round 9
// baseline (593.709 us; speedup 1.0000x reference)
//
#include <hip/hip_runtime.h>
#include <hip/hip_bf16.h>
#include <hip/hip_cooperative_groups.h>

namespace cg = cooperative_groups;

// 3-layer tanh RNN. B=32, T=64, D_IN=10000, H=200, N_CLASSES=2.
//
// R16:
//  * MEGA-KERNEL: cross-round arithmetic showed ~86us (27%) of total is
//    inter-launch gaps (~11us x 8 boundaries; R8->R9's -4 launches = -61us
//    confirmed independently). All 9 kernels fused into ONE cooperative
//    kernel with grid.sync() phase barriers. Phases are grid-stride jobs;
//    grid sized by host occupancy query (co-residency guaranteed).
//  * gemm REVERTED to R14-exact (A via LDS frag-order staging): R15's
//    A-direct + atomics regressed 49.7->83.5us (scattered 16-line wave
//    loads + 6.5M contended atomicAdds). Non-atomic partials + reduce
//    phase restored.
//  * gemm_job / rec_job are __noinline__ device functions: separately
//    register-allocated, best available shield for the rec regalloc
//    lottery (R9-R12 lesson: whole-function context flips w[80] to
//    scratch). rec body is R7-verbatim inside.
//  * LDS: one 68KB union (gemm Ab+Bb | rec preS/h/bias/part).
//  * split-bf16 3-term everywhere: ~fp32 accuracy at bf16 MFMA rate.

typedef __bf16  bf16x8 __attribute__((ext_vector_type(8)));
typedef __bf16  bf16x4 __attribute__((ext_vector_type(4)));
typedef float   f32x4  __attribute__((ext_vector_type(4)));

#define HDIM 200
#define BM 64
#define CHUNK_B 26624   // bytes per packed k-chunk: hi 13 tiles x 1KB, lo same
#define MFMA(a, b, c) __builtin_amdgcn_mfma_f32_16x16x32_bf16(a, b, c, 0, 0, 0)

__device__ __forceinline__ void glds16(const void* g, void* l) {
    __builtin_amdgcn_global_load_lds(
        (const __attribute__((address_space(1))) unsigned int*)g,
        (__attribute__((address_space(3))) unsigned int*)l, 16, 0, 0);
}

__device__ __forceinline__ float fast_tanh(float x) {
    float e = __expf(-2.f * fabsf(x));
    float r = (1.f - e) / (1.f + e);
    return copysignf(r, x);
}

// LDS-only barrier: waits LDS ops, NOT in-flight global stores (no vmcnt).
__device__ __forceinline__ void bar_lds() {
    asm volatile("s_waitcnt lgkmcnt(0)" ::: "memory");
    __builtin_amdgcn_s_barrier();
}

struct MegaArgs {
    const float *x;
    const float *Wih0, *Whh0, *bih0, *bhh0;
    const float *Wih1, *Whh1, *bih1, *bhh1;
    const float *Wih2, *Whh2, *bih2, *bhh2;
    const float *fcw, *fcb;
    float *out;
    float *P, *Hbuf, *Hbuf2, *Ppart;
    __bf16 *W0p, *W1p, *W2p;
};

// ---- one GEMM tile-job (R14-exact body). Ab: 2x4096 bf16, Bb: 2x13312. ----
__device__ __noinline__ void gemm_job(
    const float* __restrict__ A, int lda, int K,
    const __bf16* __restrict__ Bpack, float* __restrict__ C,
    int ksteps, int kc0, int m0,
    __bf16* Ab, __bf16* Bb, int tid)
{
    const int wv = tid >> 6, lane = tid & 63;
    const int r16 = lane & 15, kg = lane >> 4;
    const int mg = wv & 1, ng = wv >> 1;
    const int nt0 = ng ? 1 + ng * 3 : 0;        // 0,4,7,10
    const int ntw = ng ? 3 : 4;
    const int fb  = lane * 8;                   // lane's fragment offset (bf16)

    const int a_row = tid >> 3;          // 0..63
    const int a_q   = tid & 7;           // float4 column group
    const float* Arow = A + (size_t)(m0 + a_row) * lda + a_q * 4;
    const int a_off = (a_row >> 4) * 512 + ((a_row & 15) + 16 * (a_q >> 1)) * 8
                    + (a_q & 1) * 4;

    f32x4 acc[2][4];
#pragma unroll
    for (int mi = 0; mi < 2; ++mi)
#pragma unroll
        for (int j = 0; j < 4; ++j) acc[mi][j] = (f32x4)0.f;

    float av[4];
    auto loadA = [&](int ks) {
        const int kb = (kc0 + ks) * 32;
        if (kb + a_q * 4 < K) {          // 4-granular, K % 4 == 0
            float4 x0 = *(const float4*)(Arow + kb);
            av[0] = x0.x; av[1] = x0.y; av[2] = x0.z; av[3] = x0.w;
        } else {
#pragma unroll
            for (int i = 0; i < 4; ++i) av[i] = 0.f;
        }
    };
    auto issueB = [&](int ks, int buf) {
        const char* src = (const char*)Bpack + (size_t)(kc0 + ks) * CHUNK_B;
        char* dst = (char*)Bb + (size_t)buf * CHUNK_B;
#pragma unroll
        for (int r = 0; r < 3; ++r)
            glds16(src + (r * 512 + tid) * 16, dst + (r * 512 + tid) * 16);
        if (tid < 128)
            glds16(src + (1536 + tid) * 16, dst + (1536 + tid) * 16);
    };

    loadA(0);
    issueB(0, 0);

    for (int ks = 0; ks < ksteps; ++ks) {
        const int cur = ks & 1, nxt = cur ^ 1;
        bf16x4 th, tl;
#pragma unroll
        for (int i = 0; i < 4; ++i) {
            __bf16 h = (__bf16)av[i];
            th[i] = h; tl[i] = (__bf16)(av[i] - (float)h);
        }
        *(bf16x4*)&Ab[cur * 4096 + a_off]        = th;
        *(bf16x4*)&Ab[cur * 4096 + 2048 + a_off] = tl;
        __syncthreads();   // drains glds B(ks) + A writes (vmcnt+lgkm)
        if (ks + 1 < ksteps) { issueB(ks + 1, nxt); loadA(ks + 1); }

        const int ao0 = (mg * 2 + 0) * 512 + fb;
        const int ao1 = (mg * 2 + 1) * 512 + fb;
        bf16x8 ah0 = *(const bf16x8*)&Ab[cur * 4096 + ao0];
        bf16x8 al0 = *(const bf16x8*)&Ab[cur * 4096 + 2048 + ao0];
        bf16x8 ah1 = *(const bf16x8*)&Ab[cur * 4096 + ao1];
        bf16x8 al1 = *(const bf16x8*)&Ab[cur * 4096 + 2048 + ao1];
#pragma unroll
        for (int j = 0; j < 4; ++j) {
            if (j < ntw) {
                const int bo = (nt0 + j) * 512 + fb;
                bf16x8 bh = *(const bf16x8*)&Bb[cur * 13312 + bo];
                bf16x8 bl = *(const bf16x8*)&Bb[cur * 13312 + 6656 + bo];
                acc[0][j] = MFMA(al0, bh, acc[0][j]);
                acc[0][j] = MFMA(ah0, bl, acc[0][j]);
                acc[0][j] = MFMA(ah0, bh, acc[0][j]);
                acc[1][j] = MFMA(al1, bh, acc[1][j]);
                acc[1][j] = MFMA(ah1, bl, acc[1][j]);
                acc[1][j] = MFMA(ah1, bh, acc[1][j]);
            }
        }
    }

    // epilogue: C/D layout col=lane&15, row=(lane>>4)*4+reg
#pragma unroll
    for (int mi = 0; mi < 2; ++mi) {
        const int rb = m0 + mg * 32 + mi * 16 + kg * 4;
#pragma unroll
        for (int j = 0; j < 4; ++j) {
            if (j < ntw) {
                const int n = (nt0 + j) * 16 + r16;
                if (n < HDIM)
#pragma unroll
                    for (int r = 0; r < 4; ++r)
                        C[(size_t)(rb + r) * HDIM + n] = acc[mi][j][r];
            }
        }
    }
    __syncthreads();   // LDS safe for next job/phase
}

// ---- one recurrence batch-job (R7-verbatim body; w[80] in VGPRs). ----
__device__ __noinline__ void rec_job(
    const float* __restrict__ pre, const float* __restrict__ Whh,
    const float* __restrict__ bih, const float* __restrict__ bhh,
    float* __restrict__ Hout, int b, int tid,
    float* __restrict__ preS, float* __restrict__ hS,
    float* __restrict__ bias, float* __restrict__ part)   // part: 10x200 flat
{
    {   // stage pre slab (coalesced)
        const float4* ps = (const float4*)(pre + (size_t)b * 64 * HDIM);
        float4* pd = (float4*)preS;
        for (int i = tid; i < 3200; i += 512) pd[i] = ps[i];
    }

    const bool act = tid < 500;
    const int g  = tid / 10;            // n-group 0..49
    const int s  = tid - g * 10;        // k-slice 0..9
    const int n0 = g * 4;
    const int k0 = s * 20;

    float w[80];
    if (act) {
#pragma unroll
        for (int j = 0; j < 4; ++j) {
            const float* wr = Whh + (size_t)(n0 + j) * HDIM + k0;
#pragma unroll
            for (int i = 0; i < 5; ++i) {
                float4 v = *(const float4*)(wr + i * 4);
                w[j * 20 + i * 4 + 0] = v.x; w[j * 20 + i * 4 + 1] = v.y;
                w[j * 20 + i * 4 + 2] = v.z; w[j * 20 + i * 4 + 3] = v.w;
            }
        }
    }
    if (tid < HDIM) { bias[tid] = bih[tid] + bhh[tid]; hS[tid] = 0.f; }
    __syncthreads();

    for (int t = 0; t < 64; ++t) {
        if (act) {
            float a0 = 0.f, a1 = 0.f, a2 = 0.f, a3 = 0.f;
#pragma unroll
            for (int i = 0; i < 5; ++i) {
                float4 hv = *(const float4*)&hS[k0 + i * 4];
                a0 += w[ 0 + i*4]*hv.x + w[ 1 + i*4]*hv.y + w[ 2 + i*4]*hv.z + w[ 3 + i*4]*hv.w;
                a1 += w[20 + i*4]*hv.x + w[21 + i*4]*hv.y + w[22 + i*4]*hv.z + w[23 + i*4]*hv.w;
                a2 += w[40 + i*4]*hv.x + w[41 + i*4]*hv.y + w[42 + i*4]*hv.z + w[43 + i*4]*hv.w;
                a3 += w[60 + i*4]*hv.x + w[61 + i*4]*hv.y + w[62 + i*4]*hv.z + w[63 + i*4]*hv.w;
            }
            float4 pv = make_float4(a0, a1, a2, a3);
            *(float4*)&part[s * HDIM + n0] = pv;
        }
        bar_lds();
        if (tid < HDIM) {
            float sum = part[0 * HDIM + tid];
#pragma unroll
            for (int r = 1; r < 10; ++r) sum += part[r * HDIM + tid];
            float v = fast_tanh(sum + preS[t * HDIM + tid] + bias[tid]);
            hS[tid] = v;
            Hout[((size_t)b * 64 + t) * HDIM + tid] = v;
        }
        bar_lds();
    }
    __syncthreads();   // LDS safe for next phase
}

// ---- the whole pipeline as one cooperative kernel ----
__global__ __launch_bounds__(512, 2)
void mega(MegaArgs a)
{
    __shared__ alignas(16) char U[69632];     // union: gemm Ab+Bb | rec bufs
    __bf16* Ab   = (__bf16*)U;                //  2 x 4096 bf16 (16 KB)
    __bf16* Bb   = (__bf16*)(U + 16384);      //  2 x 13312 bf16 (53.2 KB)
    float*  preS = (float*)U;                 //  12800 f
    float*  hS   = (float*)(U + 51200);       //  200 f
    float*  bias = (float*)(U + 52000);       //  200 f
    float*  part = (float*)(U + 52800);       //  10 x 200 f

    const int tid = threadIdx.x;
    const int bid = blockIdx.x;
    const int nb  = gridDim.x;
    cg::grid_group grd = cg::this_grid();

    // ---- P0: pack all weights (fragment order, hi/lo) ----
    {
        const int T0 = 320 * 1664, T1 = 7 * 1664, T2 = 7 * 1664;
        for (int gt = bid * 512 + tid; gt < T0 + T1 + T2; gt += nb * 512) {
            const float* W; __bf16* outp; int K, g;
            if (gt < T0)           { W = a.Wih0; outp = a.W0p; K = 10000; g = gt; }
            else if (gt < T0 + T1) { W = a.Wih1; outp = a.W1p; K = HDIM;  g = gt - T0; }
            else                   { W = a.Wih2; outp = a.W2p; K = HDIM;  g = gt - T0 - T1; }
            const int kc = g / 1664;
            const int u  = g - kc * 1664;
            const int isLo = (u >= 832);
            const int u2 = isLo ? u - 832 : u;
            const int nt = u2 >> 6;
            const int l  = u2 & 63;
            const int r  = nt * 16 + (l & 15);
            const int k  = kc * 32 + (l >> 4) * 8;
            bf16x8 v;
            if (r < HDIM && k < K) {
                const float* p = W + (size_t)r * K + k;
                float4 aa = *(const float4*)p, bb = *(const float4*)(p + 4);
                float f[8] = {aa.x, aa.y, aa.z, aa.w, bb.x, bb.y, bb.z, bb.w};
#pragma unroll
                for (int i = 0; i < 8; ++i) {
                    __bf16 h = (__bf16)f[i];
                    v[i] = isLo ? (__bf16)(f[i] - (float)h) : h;
                }
            } else {
#pragma unroll
                for (int i = 0; i < 8; ++i) v[i] = (__bf16)0.f;
            }
            *(bf16x8*)&outp[(size_t)g * 8] = v;
        }
    }
    grd.sync();

    // ---- P1: gemm L0 (512 jobs: 32 m-blocks x 16 k-splits, partials) ----
    for (int job = bid; job < 32 * 16; job += nb) {
        const int mb = job & 31, ys = job >> 5;
        gemm_job(a.x, 10000, 10000, a.W0p,
                 a.Ppart + (size_t)ys * (2048 * HDIM),
                 20, ys * 20, mb * BM, Ab, Bb, tid);
    }
    grd.sync();

    // ---- P2: reduce 16 partials -> P ----
    for (int i = bid * 512 + tid; i < 102400; i += nb * 512) {
        float4 s4 = ((const float4*)a.Ppart)[i];
#pragma unroll
        for (int r = 1; r < 16; ++r) {
            float4 v = ((const float4*)a.Ppart)[(size_t)r * 102400 + i];
            s4.x += v.x; s4.y += v.y; s4.z += v.z; s4.w += v.w;
        }
        ((float4*)a.P)[i] = s4;
    }
    grd.sync();

    // ---- P3: rec L0 ----
    for (int b = bid; b < 32; b += nb)
        rec_job(a.P, a.Whh0, a.bih0, a.bhh0, a.Hbuf, b, tid, preS, hS, bias, part);
    grd.sync();

    // ---- P4: gemm L1 (32 jobs, K=200) ----
    for (int job = bid; job < 32; job += nb)
        gemm_job(a.Hbuf, HDIM, HDIM, a.W1p, a.P, 7, 0, job * BM, Ab, Bb, tid);
    grd.sync();

    // ---- P5: rec L1 ----
    for (int b = bid; b < 32; b += nb)
        rec_job(a.P, a.Whh1, a.bih1, a.bhh1, a.Hbuf2, b, tid, preS, hS, bias, part);
    grd.sync();

    // ---- P6: gemm L2 ----
    for (int job = bid; job < 32; job += nb)
        gemm_job(a.Hbuf2, HDIM, HDIM, a.W2p, a.P, 7, 0, job * BM, Ab, Bb, tid);
    grd.sync();

    // ---- P7: rec L2 ----
    for (int b = bid; b < 32; b += nb)
        rec_job(a.P, a.Whh2, a.bih2, a.bhh2, a.Hbuf, b, tid, preS, hS, bias, part);
    grd.sync();

    // ---- P8: FC head ----
    if (bid == 0 && tid < 64) {
        const int b = tid >> 1, cls = tid & 1;
        const float* hp = a.Hbuf + ((size_t)b * 64 + 63) * HDIM;
        const float* fw = a.fcw + cls * HDIM;
        float s = a.fcb[cls];
        for (int j = 0; j < HDIM; ++j) s += hp[j] * fw[j];
        a.out[b * 2 + cls] = s;
    }
}

extern "C" void kernel_launch(void* const* d_in, const int* in_sizes, int n_in,
                              void* d_out, int out_size, void* d_ws, size_t ws_size,
                              hipStream_t stream) {
    MegaArgs ma;
    ma.x    = (const float*)d_in[0];
    ma.Wih0 = (const float*)d_in[1];  ma.Whh0 = (const float*)d_in[2];
    ma.bih0 = (const float*)d_in[3];  ma.bhh0 = (const float*)d_in[4];
    ma.Wih1 = (const float*)d_in[5];  ma.Whh1 = (const float*)d_in[6];
    ma.bih1 = (const float*)d_in[7];  ma.bhh1 = (const float*)d_in[8];
    ma.Wih2 = (const float*)d_in[9];  ma.Whh2 = (const float*)d_in[10];
    ma.bih2 = (const float*)d_in[11]; ma.bhh2 = (const float*)d_in[12];
    ma.fcw  = (const float*)d_in[13]; ma.fcb  = (const float*)d_in[14];
    ma.out  = (float*)d_out;

    const size_t PE = (size_t)2048 * HDIM;          // 409600
    ma.P     = (float*)d_ws;
    ma.Hbuf  = ma.P + PE;
    ma.Hbuf2 = ma.Hbuf + PE;
    ma.Ppart = ma.Hbuf2 + PE;                       // 16 x 409600
    ma.W0p   = (__bf16*)(ma.Ppart + 16 * PE);       // 320 chunks x 13312 bf16
    ma.W1p   = ma.W0p + (size_t)320 * 13312;        // 7 chunks
    ma.W2p   = ma.W1p + (size_t)7 * 13312;
    // total ws: ~40.0 MB

    int maxb = 1;
    hipOccupancyMaxActiveBlocksPerMultiprocessor(&maxb, mega, 512, 0);
    if (maxb < 1) maxb = 1;
    int grid = maxb * 256;
    if (grid > 512) grid = 512;

    void* kargs[] = { (void*)&ma };
    hipLaunchCooperativeKernel((const void*)mega, dim3(grid), dim3(512),
                               kargs, 0, stream);
}

// Round 10
// 328.995 us; speedup vs baseline: 1.8046x; 1.8046x over previous
//
#include <hip/hip_runtime.h>
#include <hip/hip_bf16.h>

// 3-layer tanh RNN. B=32, T=64, D_IN=10000, H=200, N_CLASSES=2.
//
// R17:
//  * R16 mega REVERTED: idle blocks spin-polling grid.sync() contended the
//    rec CUs (rec 47->~120us) + w[80] scratch (VGPR=92). Cooperative
//    heterogeneous phases = structurally wrong here.
//  * CHAIN KERNEL (the right fusion): after gemm L0, everything is
//    per-batch independent: rec_l(b) <- pre_l(b) <- H_{l-1}(b), same b.
//    One plain 32-block kernel runs rec0 -> gemm1 -> rec1 -> gemm2 ->
//    rec2 -> fc per batch. No cross-block sync, no spinners, 1 block/CU.
//    Inter-layer gemms = one gemm_job tile each (m0=0, lda=200, 7 ksteps,
//    reusing packed W1p/W2p). 9 launches -> 4 (saves ~5 x ~12us gaps).
//  * rec body R7-VERBATIM text inline in the chain (R7/R13 precedent for
//    winning the w[80] regalloc lottery); gemm_job is __noinline__.
//  * P reused as pre buffer for all layers (block b consumes its slab
//    before overwriting it); Hbuf reused for all layers' H.
//  * gemm L0 / reduce_parts / pack_all: R13-proven versions (frag-order).
//  * split-bf16 3-term everywhere: ~fp32 accuracy at bf16 MFMA rate.

typedef __bf16  bf16x8 __attribute__((ext_vector_type(8)));
typedef __bf16  bf16x4 __attribute__((ext_vector_type(4)));
typedef float   f32x4  __attribute__((ext_vector_type(4)));

#define HDIM 200
#define BM 64
#define CHUNK_B 26624   // bytes per packed k-chunk: hi 13 tiles x 1KB, lo same
#define MFMA(a, b, c) __builtin_amdgcn_mfma_f32_16x16x32_bf16(a, b, c, 0, 0, 0)

__device__ __forceinline__ void glds16(const void* g, void* l) {
    __builtin_amdgcn_global_load_lds(
        (const __attribute__((address_space(1))) unsigned int*)g,
        (__attribute__((address_space(3))) unsigned int*)l, 16, 0, 0);
}

__device__ __forceinline__ float fast_tanh(float x) {
    float e = __expf(-2.f * fabsf(x));
    float r = (1.f - e) / (1.f + e);
    return copysignf(r, x);
}

// LDS-only barrier: waits LDS ops, NOT in-flight global stores (no vmcnt).
__device__ __forceinline__ void bar_lds() {
    asm volatile("s_waitcnt lgkmcnt(0)" ::: "memory");
    __builtin_amdgcn_s_barrier();
}

// ---- pack W [HDIM x K] fp32 -> chunks in FRAGMENT ORDER (R14-proven) ----
__global__ void pack_all(const float* __restrict__ W0,
                         const float* __restrict__ W1,
                         const float* __restrict__ W2,
                         __bf16* __restrict__ O0,
                         __bf16* __restrict__ O1,
                         __bf16* __restrict__ O2)
{
    const int T0 = 320 * 1664, T1 = 7 * 1664, T2 = 7 * 1664;
    for (int gt = blockIdx.x * blockDim.x + threadIdx.x; gt < T0 + T1 + T2;
         gt += gridDim.x * blockDim.x) {
        const float* W; __bf16* out; int K, g;
        if (gt < T0)           { W = W0; out = O0; K = 10000; g = gt; }
        else if (gt < T0 + T1) { W = W1; out = O1; K = HDIM;  g = gt - T0; }
        else                   { W = W2; out = O2; K = HDIM;  g = gt - T0 - T1; }

        const int kc = g / 1664;
        const int u  = g - kc * 1664;
        const int isLo = (u >= 832);
        const int u2 = isLo ? u - 832 : u;
        const int nt = u2 >> 6;              // n-tile 0..12
        const int l  = u2 & 63;              // lane slot
        const int r  = nt * 16 + (l & 15);   // 0..207
        const int k  = kc * 32 + (l >> 4) * 8;
        bf16x8 v;
        if (r < HDIM && k < K) {             // K % 8 == 0
            const float* p = W + (size_t)r * K + k;
            float4 a = *(const float4*)p, b = *(const float4*)(p + 4);
            float f[8] = {a.x, a.y, a.z, a.w, b.x, b.y, b.z, b.w};
#pragma unroll
            for (int i = 0; i < 8; ++i) {
                __bf16 h = (__bf16)f[i];
                v[i] = isLo ? (__bf16)(f[i] - (float)h) : h;
            }
        } else {
#pragma unroll
            for (int i = 0; i < 8; ++i) v[i] = (__bf16)0.f;
        }
        *(bf16x8*)&out[(size_t)g * 8] = v;
    }
}

// ---- one GEMM tile-job (R14-exact body). Ab: 2x4096 bf16, Bb: 2x13312. ----
__device__ __noinline__ void gemm_job(
    const float* __restrict__ A, int lda, int K,
    const __bf16* __restrict__ Bpack, float* __restrict__ C,
    int ksteps, int kc0, int m0,
    __bf16* Ab, __bf16* Bb, int tid)
{
    const int wv = tid >> 6, lane = tid & 63;
    const int r16 = lane & 15, kg = lane >> 4;
    const int mg = wv & 1, ng = wv >> 1;
    const int nt0 = ng ? 1 + ng * 3 : 0;        // 0,4,7,10
    const int ntw = ng ? 3 : 4;
    const int fb  = lane * 8;                   // lane's fragment offset (bf16)

    const int a_row = tid >> 3;          // 0..63
    const int a_q   = tid & 7;           // float4 column group
    const float* Arow = A + (size_t)(m0 + a_row) * lda + a_q * 4;
    const int a_off = (a_row >> 4) * 512 + ((a_row & 15) + 16 * (a_q >> 1)) * 8
                    + (a_q & 1) * 4;

    f32x4 acc[2][4];
#pragma unroll
    for (int mi = 0; mi < 2; ++mi)
#pragma unroll
        for (int j = 0; j < 4; ++j) acc[mi][j] = (f32x4)0.f;

    float av[4];
    auto loadA = [&](int ks) {
        const int kb = (kc0 + ks) * 32;
        if (kb + a_q * 4 < K) {          // 4-granular, K % 4 == 0
            float4 x0 = *(const float4*)(Arow + kb);
            av[0] = x0.x; av[1] = x0.y; av[2] = x0.z; av[3] = x0.w;
        } else {
#pragma unroll
            for (int i = 0; i < 4; ++i) av[i] = 0.f;
        }
    };
    auto issueB = [&](int ks, int buf) {
        const char* src = (const char*)Bpack + (size_t)(kc0 + ks) * CHUNK_B;
        char* dst = (char*)Bb + (size_t)buf * CHUNK_B;
#pragma unroll
        for (int r = 0; r < 3; ++r)
            glds16(src + (r * 512 + tid) * 16, dst + (r * 512 + tid) * 16);
        if (tid < 128)
            glds16(src + (1536 + tid) * 16, dst + (1536 + tid) * 16);
    };

    loadA(0);
    issueB(0, 0);

    for (int ks = 0; ks < ksteps; ++ks) {
        const int cur = ks & 1, nxt = cur ^ 1;
        bf16x4 th, tl;
#pragma unroll
        for (int i = 0; i < 4; ++i) {
            __bf16 h = (__bf16)av[i];
            th[i] = h; tl[i] = (__bf16)(av[i] - (float)h);
        }
        *(bf16x4*)&Ab[cur * 4096 + a_off]        = th;
        *(bf16x4*)&Ab[cur * 4096 + 2048 + a_off] = tl;
        __syncthreads();   // drains glds B(ks) + A writes (vmcnt+lgkm)
        if (ks + 1 < ksteps) { issueB(ks + 1, nxt); loadA(ks + 1); }

        const int ao0 = (mg * 2 + 0) * 512 + fb;
        const int ao1 = (mg * 2 + 1) * 512 + fb;
        bf16x8 ah0 = *(const bf16x8*)&Ab[cur * 4096 + ao0];
        bf16x8 al0 = *(const bf16x8*)&Ab[cur * 4096 + 2048 + ao0];
        bf16x8 ah1 = *(const bf16x8*)&Ab[cur * 4096 + ao1];
        bf16x8 al1 = *(const bf16x8*)&Ab[cur * 4096 + 2048 + ao1];
#pragma unroll
        for (int j = 0; j < 4; ++j) {
            if (j < ntw) {
                const int bo = (nt0 + j) * 512 + fb;
                bf16x8 bh = *(const bf16x8*)&Bb[cur * 13312 + bo];
                bf16x8 bl = *(const bf16x8*)&Bb[cur * 13312 + 6656 + bo];
                acc[0][j] = MFMA(al0, bh, acc[0][j]);
                acc[0][j] = MFMA(ah0, bl, acc[0][j]);
                acc[0][j] = MFMA(ah0, bh, acc[0][j]);
                acc[1][j] = MFMA(al1, bh, acc[1][j]);
                acc[1][j] = MFMA(ah1, bl, acc[1][j]);
                acc[1][j] = MFMA(ah1, bh, acc[1][j]);
            }
        }
    }

    // epilogue: C/D layout col=lane&15, row=(lane>>4)*4+reg
#pragma unroll
    for (int mi = 0; mi < 2; ++mi) {
        const int rb = m0 + mg * 32 + mi * 16 + kg * 4;
#pragma unroll
        for (int j = 0; j < 4; ++j) {
            if (j < ntw) {
                const int n = (nt0 + j) * 16 + r16;
                if (n < HDIM)
#pragma unroll
                    for (int r = 0; r < 4; ++r)
                        C[(size_t)(rb + r) * HDIM + n] = acc[mi][j][r];
            }
        }
    }
    __syncthreads();   // drains loads/stores; LDS safe for next phase
}

// ---- L0 GEMM wrapper: grid (32 m-blocks, 16 k-splits) ----
__global__ __launch_bounds__(512, 4)
void gemm_l0(const float* __restrict__ x, const __bf16* __restrict__ W0p,
             float* __restrict__ Ppart, int per_split)
{
    __shared__ alignas(16) char U[69632];
    gemm_job(x, 10000, 10000, W0p,
             Ppart + (size_t)blockIdx.y * per_split,
             20, blockIdx.y * 20, blockIdx.x * BM,
             (__bf16*)U, (__bf16*)(U + 16384), threadIdx.x);
}

// ---- sum 16 k-split partials ----
__global__ void reduce_parts(const float* __restrict__ Pp, float* __restrict__ P)
{
    const int i = blockIdx.x * blockDim.x + threadIdx.x;   // float4 index
    if (i < 102400) {
        float4 s = ((const float4*)Pp)[i];
#pragma unroll
        for (int r = 1; r < 16; ++r) {
            float4 v = ((const float4*)Pp)[(size_t)r * 102400 + i];
            s.x += v.x; s.y += v.y; s.z += v.z; s.w += v.w;
        }
        ((float4*)P)[i] = s;
    }
}

// ---- per-batch chain: rec0 -> gemm1 -> rec1 -> gemm2 -> rec2 -> fc ----
// 32 blocks, 1 per batch, no cross-block deps. P is read AND rewritten
// (each block only touches its own slab, consumed before overwrite).
__global__ __launch_bounds__(512, 1)
void rnn_chain(float* P, float* Hbuf,
               const float* __restrict__ Whh0, const float* __restrict__ bih0,
               const float* __restrict__ bhh0,
               const float* __restrict__ Whh1, const float* __restrict__ bih1,
               const float* __restrict__ bhh1,
               const float* __restrict__ Whh2, const float* __restrict__ bih2,
               const float* __restrict__ bhh2,
               const __bf16* __restrict__ W1p, const __bf16* __restrict__ W2p,
               const float* __restrict__ fcw, const float* __restrict__ fcb,
               float* __restrict__ outp)
{
    const int b   = blockIdx.x;
    const int tid = threadIdx.x;

    __shared__ alignas(16) char U[69632];     // union: gemm Ab+Bb | rec bufs
    __bf16* Ab   = (__bf16*)U;
    __bf16* Bb   = (__bf16*)(U + 16384);
    float*  preS = (float*)U;                 // 12800 f
    float*  hS   = (float*)(U + 51200);       // 200 f
    float*  bias = (float*)(U + 52000);       // 200 f
    float*  part = (float*)(U + 52800);       // 10 x 200 f

    // R7-verbatim recurrence body (text preserved; only names adapted).
    auto rec = [&](const float* pre, const float* Whh, const float* bih,
                   const float* bhh, float* Hout) {
        {   // stage pre slab (coalesced)
            const float4* ps = (const float4*)(pre + (size_t)b * 64 * HDIM);
            float4* pd = (float4*)preS;
            for (int i = tid; i < 3200; i += 512) pd[i] = ps[i];
        }

        const bool act = tid < 500;
        const int g  = tid / 10;            // n-group 0..49
        const int s  = tid - g * 10;        // k-slice 0..9
        const int n0 = g * 4;
        const int k0 = s * 20;

        float w[80];
        if (act) {
#pragma unroll
            for (int j = 0; j < 4; ++j) {
                const float* wr = Whh + (size_t)(n0 + j) * HDIM + k0;
#pragma unroll
                for (int i = 0; i < 5; ++i) {
                    float4 v = *(const float4*)(wr + i * 4);
                    w[j * 20 + i * 4 + 0] = v.x; w[j * 20 + i * 4 + 1] = v.y;
                    w[j * 20 + i * 4 + 2] = v.z; w[j * 20 + i * 4 + 3] = v.w;
                }
            }
        }
        if (tid < HDIM) { bias[tid] = bih[tid] + bhh[tid]; hS[tid] = 0.f; }
        __syncthreads();

        for (int t = 0; t < 64; ++t) {
            if (act) {
                float a0 = 0.f, a1 = 0.f, a2 = 0.f, a3 = 0.f;
#pragma unroll
                for (int i = 0; i < 5; ++i) {
                    float4 hv = *(const float4*)&hS[k0 + i * 4];
                    a0 += w[ 0 + i*4]*hv.x + w[ 1 + i*4]*hv.y + w[ 2 + i*4]*hv.z + w[ 3 + i*4]*hv.w;
                    a1 += w[20 + i*4]*hv.x + w[21 + i*4]*hv.y + w[22 + i*4]*hv.z + w[23 + i*4]*hv.w;
                    a2 += w[40 + i*4]*hv.x + w[41 + i*4]*hv.y + w[42 + i*4]*hv.z + w[43 + i*4]*hv.w;
                    a3 += w[60 + i*4]*hv.x + w[61 + i*4]*hv.y + w[62 + i*4]*hv.z + w[63 + i*4]*hv.w;
                }
                float4 pv = make_float4(a0, a1, a2, a3);
                *(float4*)&part[s * HDIM + n0] = pv;
            }
            bar_lds();
            if (tid < HDIM) {
                float sum = part[0 * HDIM + tid];
#pragma unroll
                for (int r = 1; r < 10; ++r) sum += part[r * HDIM + tid];
                float v = fast_tanh(sum + preS[t * HDIM + tid] + bias[tid]);
                hS[tid] = v;
                Hout[((size_t)b * 64 + t) * HDIM + tid] = v;
            }
            bar_lds();
        }
    };

    float* Hslab = Hbuf + (size_t)b * 64 * HDIM;
    float* Pslab = P + (size_t)b * 64 * HDIM;

    rec(P, Whh0, bih0, bhh0, Hbuf);
    __syncthreads();                          // drain Hout stores before gemm reads
    gemm_job(Hslab, HDIM, HDIM, W1p, Pslab, 7, 0, 0, Ab, Bb, tid);

    rec(P, Whh1, bih1, bhh1, Hbuf);
    __syncthreads();
    gemm_job(Hslab, HDIM, HDIM, W2p, Pslab, 7, 0, 0, Ab, Bb, tid);

    rec(P, Whh2, bih2, bhh2, Hbuf);

    // fc head: hS holds h_63 (bar_lds made it LDS-visible)
    if (tid < 16) {
        const int cls = tid & 1, sl = tid >> 1;      // 8 slices of 25
        const float* fw = fcw + cls * HDIM + sl * 25;
        const float* hp = hS + sl * 25;
        float sacc = 0.f;
#pragma unroll
        for (int j = 0; j < 25; ++j) sacc += hp[j] * fw[j];
        sacc += __shfl_xor(sacc, 2);
        sacc += __shfl_xor(sacc, 4);
        sacc += __shfl_xor(sacc, 8);
        if (sl == 0) outp[b * 2 + cls] = sacc + fcb[cls];
    }
}

extern "C" void kernel_launch(void* const* d_in, const int* in_sizes, int n_in,
                              void* d_out, int out_size, void* d_ws, size_t ws_size,
                              hipStream_t stream) {
    const float* x     = (const float*)d_in[0];
    const float* W_ih0 = (const float*)d_in[1];
    const float* W_hh0 = (const float*)d_in[2];
    const float* b_ih0 = (const float*)d_in[3];
    const float* b_hh0 = (const float*)d_in[4];
    const float* W_ih1 = (const float*)d_in[5];
    const float* W_hh1 = (const float*)d_in[6];
    const float* b_ih1 = (const float*)d_in[7];
    const float* b_hh1 = (const float*)d_in[8];
    const float* W_ih2 = (const float*)d_in[9];
    const float* W_hh2 = (const float*)d_in[10];
    const float* b_ih2 = (const float*)d_in[11];
    const float* b_hh2 = (const float*)d_in[12];
    const float* fc_w  = (const float*)d_in[13];
    const float* fc_b  = (const float*)d_in[14];
    float* out = (float*)d_out;

    const size_t PE = (size_t)2048 * HDIM;          // 409600
    float* P     = (float*)d_ws;
    float* Hbuf  = P + PE;
    float* Ppart = Hbuf + PE;                       // 16 x 409600
    __bf16* W0p  = (__bf16*)(Ppart + 16 * PE);      // 320 chunks x 13312 bf16
    __bf16* W1p  = W0p + (size_t)320 * 13312;       // 7 chunks
    __bf16* W2p  = W1p + (size_t)7 * 13312;
    // total ws: ~38 MB

    // ---- 4 launches total ----
    pack_all<<<1024, 256, 0, stream>>>(W_ih0, W_ih1, W_ih2, W0p, W1p, W2p);
    gemm_l0<<<dim3(32, 16), 512, 0, stream>>>(x, W0p, Ppart, (int)PE);
    reduce_parts<<<400, 256, 0, stream>>>(Ppart, P);
    rnn_chain<<<32, 512, 0, stream>>>(P, Hbuf,
                                      W_hh0, b_ih0, b_hh0,
                                      W_hh1, b_ih1, b_hh1,
                                      W_hh2, b_ih2, b_hh2,
                                      W1p, W2p, fc_w, fc_b, out);
}